// Round 8
// baseline (267.193 us; speedup 1.0000x reference)
//
#include <hip/hip_runtime.h>

#define NCLS 21
#define BLK 256
#define APT 2
#define SPAN (BLK * APT)   // 512 anchors per block

// Unaligned (4B-aligned) 16-byte global load -> global_load_dwordx4.
__device__ __forceinline__ float4 load_f4u(const float* p) {
    float4 v; __builtin_memcpy(&v, p, 16); return v;
}

__device__ __forceinline__ float fmax4(const float4& v) {
    return fmaxf(fmaxf(v.x, v.y), fmaxf(v.z, v.w));
}
__device__ __forceinline__ float4 fmax44(const float4& a, const float4& b) {
    return make_float4(fmaxf(a.x, b.x), fmaxf(a.y, b.y),
                       fmaxf(a.z, b.z), fmaxf(a.w, b.w));
}

// Focal term, pure registers; row[t] extraction fused as compare-select.
__device__ __forceinline__ float focal_regs(
    int t, const float4& c0, const float4& c1, const float4& c2,
    const float4& c3, const float4& c4, float c20)
{
    float m = fmaxf(fmax4(fmax44(fmax44(c0, c1), fmax44(c2, c3))),
                    fmaxf(fmax4(c4), c20));
    float s = 0.0f, et = 0.0f;
#define FSTEP(val, idx) { float e = __expf((val) - m); s += e; et = (t == (idx)) ? e : et; }
    FSTEP(c0.x, 0)  FSTEP(c0.y, 1)  FSTEP(c0.z, 2)  FSTEP(c0.w, 3)
    FSTEP(c1.x, 4)  FSTEP(c1.y, 5)  FSTEP(c1.z, 6)  FSTEP(c1.w, 7)
    FSTEP(c2.x, 8)  FSTEP(c2.y, 9)  FSTEP(c2.z, 10) FSTEP(c2.w, 11)
    FSTEP(c3.x, 12) FSTEP(c3.y, 13) FSTEP(c3.z, 14) FSTEP(c3.w, 15)
    FSTEP(c4.x, 16) FSTEP(c4.y, 17) FSTEP(c4.z, 18) FSTEP(c4.w, 19)
    FSTEP(c20,  20)
#undef FSTEP
    float pt = et / s;
    pt = fminf(fmaxf(pt, 1e-7f), 1.0f - 1e-7f);
    float om = 1.0f - pt;
    return -__logf(pt) * om * om;
}

__device__ __forceinline__ float smooth_l1(const float4& lp, const float4& lt) {
    float d0 = lp.x - lt.x, d1 = lp.y - lt.y, d2 = lp.z - lt.z, d3 = lp.w - lt.w;
    float a0 = fabsf(d0), a1 = fabsf(d1), a2 = fabsf(d2), a3 = fabsf(d3);
    float s = 0.0f;
    s += (a0 < 1.0f) ? 0.5f * d0 * d0 : a0 - 0.5f;
    s += (a1 < 1.0f) ? 0.5f * d1 * d1 : a1 - 0.5f;
    s += (a2 < 1.0f) ? 0.5f * d2 * d2 : a2 - 0.5f;
    s += (a3 < 1.0f) ? 0.5f * d3 * d3 : a3 - 0.5f;
    return s;
}

__global__ __launch_bounds__(BLK) void focal_fused(
    const float* __restrict__ loc_p,
    const float* __restrict__ loc_t,
    const float* __restrict__ cls_p,
    const int*   __restrict__ cls_t,
    unsigned int* __restrict__ counter,   // ws[0..3], memset to 0
    float*        __restrict__ pf,        // ws+16: per-block (L,P) pairs
    float*        __restrict__ out,
    int n_anchors, int nblocks)
{
    __shared__ float redL[4], redP[4];
    __shared__ int last_flag;

    const int tid  = threadIdx.x;
    const int wave = tid >> 6;
    const int lane = tid & 63;
    // 32-bit indices: max byte offset = 1M*21*4 = 88 MB < 2^31
    const unsigned a0 = (unsigned)blockIdx.x * SPAN + tid;
    const unsigned a1 = a0 + BLK;

    float acc = 0.0f, npos = 0.0f;
    const bool v0 = (a0 < (unsigned)n_anchors), v1 = (a1 < (unsigned)n_anchors);

    // ---- all loads into named registers, issued before any use ----
    int t0 = -1, t1 = -1;
    float4 lp0, lt0, lp1, lt1;
    float4 c00, c01, c02, c03, c04; float c0_20 = 0.0f;
    float4 c10, c11, c12, c13, c14; float c1_20 = 0.0f;

    if (v0) {
        t0  = cls_t[a0];
        lp0 = ((const float4*)loc_p)[a0];
        lt0 = ((const float4*)loc_t)[a0];
        const float* g = cls_p + a0 * NCLS;
        c00 = load_f4u(g);      c01 = load_f4u(g + 4);  c02 = load_f4u(g + 8);
        c03 = load_f4u(g + 12); c04 = load_f4u(g + 16); c0_20 = g[20];
    }
    if (v1) {
        t1  = cls_t[a1];
        lp1 = ((const float4*)loc_p)[a1];
        lt1 = ((const float4*)loc_t)[a1];
        const float* g = cls_p + a1 * NCLS;
        c10 = load_f4u(g);      c11 = load_f4u(g + 4);  c12 = load_f4u(g + 8);
        c13 = load_f4u(g + 12); c14 = load_f4u(g + 16); c1_20 = g[20];
    }

    // ---- pure-register compute ----
    if (v0) {
        if (t0 > 0)  { acc += smooth_l1(lp0, lt0); npos += 1.0f; }
        if (t0 >= 0) acc += focal_regs(t0, c00, c01, c02, c03, c04, c0_20);
    }
    if (v1) {
        if (t1 > 0)  { acc += smooth_l1(lp1, lt1); npos += 1.0f; }
        if (t1 >= 0) acc += focal_regs(t1, c10, c11, c12, c13, c14, c1_20);
    }

    // ---- wave shuffle -> LDS -> one (L,P) per block ----
    #pragma unroll
    for (int off = 32; off > 0; off >>= 1) {
        acc  += __shfl_down(acc,  off, 64);
        npos += __shfl_down(npos, off, 64);
    }
    if (lane == 0) { redL[wave] = acc; redP[wave] = npos; }
    __syncthreads();

    if (tid == 0) {
        float L = redL[0] + redL[1] + redL[2] + redL[3];
        float P = redP[0] + redP[1] + redP[2] + redP[3];
        __hip_atomic_store(&pf[2 * blockIdx.x],     L, __ATOMIC_RELAXED, __HIP_MEMORY_SCOPE_AGENT);
        __hip_atomic_store(&pf[2 * blockIdx.x + 1], P, __ATOMIC_RELAXED, __HIP_MEMORY_SCOPE_AGENT);
        unsigned int old = __hip_atomic_fetch_add(counter, 1u, __ATOMIC_ACQ_REL,
                                                  __HIP_MEMORY_SCOPE_AGENT);
        last_flag = (old == (unsigned int)(nblocks - 1));
    }
    __syncthreads();

    // ---- last arriving block reduces the 2048 partials and writes out ----
    if (last_flag) {
        float L = 0.0f, P = 0.0f;
        for (int i = tid; i < nblocks; i += BLK) {
            L += __hip_atomic_load(&pf[2 * i],     __ATOMIC_RELAXED, __HIP_MEMORY_SCOPE_AGENT);
            P += __hip_atomic_load(&pf[2 * i + 1], __ATOMIC_RELAXED, __HIP_MEMORY_SCOPE_AGENT);
        }
        #pragma unroll
        for (int off = 32; off > 0; off >>= 1) {
            L += __shfl_down(L, off, 64);
            P += __shfl_down(P, off, 64);
        }
        if (lane == 0) { redL[wave] = L; redP[wave] = P; }
        __syncthreads();
        if (tid == 0) {
            float Ls = redL[0] + redL[1] + redL[2] + redL[3];
            float Ps = redP[0] + redP[1] + redP[2] + redP[3];
            out[0] = Ls / Ps;
        }
    }
}

extern "C" void kernel_launch(void* const* d_in, const int* in_sizes, int n_in,
                              void* d_out, int out_size, void* d_ws, size_t ws_size,
                              hipStream_t stream)
{
    const float* loc_p = (const float*)d_in[0];
    const float* loc_t = (const float*)d_in[1];
    const float* cls_p = (const float*)d_in[2];
    const int*   cls_t = (const int*)d_in[3];
    // d_in[4] (pos) ignored: pos == (cls_targets > 0) exactly.
    float* out = (float*)d_out;

    unsigned int* counter = (unsigned int*)d_ws;
    float* pf = (float*)((char*)d_ws + 16);

    const int n_anchors = in_sizes[3];                  // B*A = 1,048,576
    const int blocks = (n_anchors + SPAN - 1) / SPAN;   // 2048

    hipMemsetAsync(d_ws, 0, 16, stream);                // counter only
    focal_fused<<<blocks, BLK, 0, stream>>>(loc_p, loc_t, cls_p, cls_t,
                                            counter, pf, out, n_anchors, blocks);
}

// Round 9
// 212.296 us; speedup vs baseline: 1.2586x; 1.2586x over previous
//
#include <hip/hip_runtime.h>

#define NCLS 21
#define BLK 256
#define APT 2
#define SPAN (BLK * APT)   // 512 anchors per block
// s_waitcnt imm: vmcnt(0), lgkmcnt/expcnt unconstrained (gfx9 encoding)
#define WAITCNT_VM0 0x0F70

// Unaligned (4B-aligned) 16-byte global load -> global_load_dwordx4.
__device__ __forceinline__ float4 load_f4u(const float* p) {
    float4 v; __builtin_memcpy(&v, p, 16); return v;
}

__device__ __forceinline__ float fmax4(const float4& v) {
    return fmaxf(fmaxf(v.x, v.y), fmaxf(v.z, v.w));
}
__device__ __forceinline__ float4 fmax44(const float4& a, const float4& b) {
    return make_float4(fmaxf(a.x, b.x), fmaxf(a.y, b.y),
                       fmaxf(a.z, b.z), fmaxf(a.w, b.w));
}

// Focal term, pure registers; row[t] extraction fused as compare-select.
__device__ __forceinline__ float focal_regs(
    int t, const float4& c0, const float4& c1, const float4& c2,
    const float4& c3, const float4& c4, float c20)
{
    float m = fmaxf(fmax4(fmax44(fmax44(c0, c1), fmax44(c2, c3))),
                    fmaxf(fmax4(c4), c20));
    float s = 0.0f, et = 0.0f;
#define FSTEP(val, idx) { float e = __expf((val) - m); s += e; et = (t == (idx)) ? e : et; }
    FSTEP(c0.x, 0)  FSTEP(c0.y, 1)  FSTEP(c0.z, 2)  FSTEP(c0.w, 3)
    FSTEP(c1.x, 4)  FSTEP(c1.y, 5)  FSTEP(c1.z, 6)  FSTEP(c1.w, 7)
    FSTEP(c2.x, 8)  FSTEP(c2.y, 9)  FSTEP(c2.z, 10) FSTEP(c2.w, 11)
    FSTEP(c3.x, 12) FSTEP(c3.y, 13) FSTEP(c3.z, 14) FSTEP(c3.w, 15)
    FSTEP(c4.x, 16) FSTEP(c4.y, 17) FSTEP(c4.z, 18) FSTEP(c4.w, 19)
    FSTEP(c20,  20)
#undef FSTEP
    float pt = et / s;
    pt = fminf(fmaxf(pt, 1e-7f), 1.0f - 1e-7f);
    float om = 1.0f - pt;
    return -__logf(pt) * om * om;
}

__device__ __forceinline__ float smooth_l1(const float4& lp, const float4& lt) {
    float d0 = lp.x - lt.x, d1 = lp.y - lt.y, d2 = lp.z - lt.z, d3 = lp.w - lt.w;
    float a0 = fabsf(d0), a1 = fabsf(d1), a2 = fabsf(d2), a3 = fabsf(d3);
    float s = 0.0f;
    s += (a0 < 1.0f) ? 0.5f * d0 * d0 : a0 - 0.5f;
    s += (a1 < 1.0f) ? 0.5f * d1 * d1 : a1 - 0.5f;
    s += (a2 < 1.0f) ? 0.5f * d2 * d2 : a2 - 0.5f;
    s += (a3 < 1.0f) ? 0.5f * d3 * d3 : a3 - 0.5f;
    return s;
}

// ws layout: [0]=counter(uint), [1]=L(float), [2]=P(float); memset to 0.
__global__ __launch_bounds__(BLK) void focal_main(
    const float* __restrict__ loc_p,
    const float* __restrict__ loc_t,
    const float* __restrict__ cls_p,
    const int*   __restrict__ cls_t,
    unsigned int* __restrict__ ws,
    float* __restrict__ out,
    int n_anchors, int nblocks)
{
    __shared__ float redL[4], redP[4];

    const int tid  = threadIdx.x;
    const int wave = tid >> 6;
    const int lane = tid & 63;
    const unsigned a0 = (unsigned)blockIdx.x * SPAN + tid;
    const unsigned a1 = a0 + BLK;

    float acc = 0.0f, npos = 0.0f;
    const bool v0 = (a0 < (unsigned)n_anchors), v1 = (a1 < (unsigned)n_anchors);

    // ---- all loads into named registers, issued before any use ----
    int t0 = -1, t1 = -1;
    float4 lp0, lt0, lp1, lt1;
    float4 c00, c01, c02, c03, c04; float c0_20 = 0.0f;
    float4 c10, c11, c12, c13, c14; float c1_20 = 0.0f;

    if (v0) {
        t0  = cls_t[a0];
        lp0 = ((const float4*)loc_p)[a0];
        lt0 = ((const float4*)loc_t)[a0];
        const float* g = cls_p + a0 * NCLS;
        c00 = load_f4u(g);      c01 = load_f4u(g + 4);  c02 = load_f4u(g + 8);
        c03 = load_f4u(g + 12); c04 = load_f4u(g + 16); c0_20 = g[20];
    }
    if (v1) {
        t1  = cls_t[a1];
        lp1 = ((const float4*)loc_p)[a1];
        lt1 = ((const float4*)loc_t)[a1];
        const float* g = cls_p + a1 * NCLS;
        c10 = load_f4u(g);      c11 = load_f4u(g + 4);  c12 = load_f4u(g + 8);
        c13 = load_f4u(g + 12); c14 = load_f4u(g + 16); c1_20 = g[20];
    }

    // ---- pure-register compute ----
    if (v0) {
        if (t0 > 0)  { acc += smooth_l1(lp0, lt0); npos += 1.0f; }
        if (t0 >= 0) acc += focal_regs(t0, c00, c01, c02, c03, c04, c0_20);
    }
    if (v1) {
        if (t1 > 0)  { acc += smooth_l1(lp1, lt1); npos += 1.0f; }
        if (t1 >= 0) acc += focal_regs(t1, c10, c11, c12, c13, c14, c1_20);
    }

    // ---- wave shuffle -> LDS -> per-block (L,P) ----
    #pragma unroll
    for (int off = 32; off > 0; off >>= 1) {
        acc  += __shfl_down(acc,  off, 64);
        npos += __shfl_down(npos, off, 64);
    }
    if (lane == 0) { redL[wave] = acc; redP[wave] = npos; }
    __syncthreads();

    // ---- cache-op-free finalize: relaxed RMWs + explicit vmcnt ordering ----
    if (tid == 0) {
        float L = redL[0] + redL[1] + redL[2] + redL[3];
        float P = redP[0] + redP[1] + redP[2] + redP[3];
        float* Lacc = (float*)(ws + 1);
        float* Pacc = (float*)(ws + 2);
        // relaxed agent-scope fp32 RMWs: execute at the coherence point, no
        // wbl2/inv cache maintenance (the R5/R8 regression mechanism)
        (void)__hip_atomic_fetch_add(Lacc, L, __ATOMIC_RELAXED, __HIP_MEMORY_SCOPE_AGENT);
        (void)__hip_atomic_fetch_add(Pacc, P, __ATOMIC_RELAXED, __HIP_MEMORY_SCOPE_AGENT);
        __atomic_signal_fence(__ATOMIC_SEQ_CST);
        __builtin_amdgcn_s_waitcnt(WAITCNT_VM0);   // L/P RMWs acked at coherence
        __atomic_signal_fence(__ATOMIC_SEQ_CST);
        unsigned int old = __hip_atomic_fetch_add(ws, 1u, __ATOMIC_RELAXED,
                                                  __HIP_MEMORY_SCOPE_AGENT);
        if (old == (unsigned int)(nblocks - 1)) {
            // last arrival: all prior L/P RMWs reached coherence before their
            // counter increments -> atomic loads see the final sums
            float Ls = __hip_atomic_load(Lacc, __ATOMIC_RELAXED, __HIP_MEMORY_SCOPE_AGENT);
            float Ps = __hip_atomic_load(Pacc, __ATOMIC_RELAXED, __HIP_MEMORY_SCOPE_AGENT);
            out[0] = Ls / Ps;
        }
    }
}

extern "C" void kernel_launch(void* const* d_in, const int* in_sizes, int n_in,
                              void* d_out, int out_size, void* d_ws, size_t ws_size,
                              hipStream_t stream)
{
    const float* loc_p = (const float*)d_in[0];
    const float* loc_t = (const float*)d_in[1];
    const float* cls_p = (const float*)d_in[2];
    const int*   cls_t = (const int*)d_in[3];
    // d_in[4] (pos) ignored: pos == (cls_targets > 0) exactly.
    float* out = (float*)d_out;
    unsigned int* ws = (unsigned int*)d_ws;

    const int n_anchors = in_sizes[3];                  // B*A = 1,048,576
    const int blocks = (n_anchors + SPAN - 1) / SPAN;   // 2048

    hipMemsetAsync(d_ws, 0, 16, stream);                // counter + L + P
    focal_main<<<blocks, BLK, 0, stream>>>(loc_p, loc_t, cls_p, cls_t,
                                           ws, out, n_anchors, blocks);
}

// Round 10
// 166.345 us; speedup vs baseline: 1.6063x; 1.2762x over previous
//
#include <hip/hip_runtime.h>

#define NCLS 21
#define BLK 256
#define APT 2
#define SPAN (BLK * APT)   // 512 anchors per block

// Unaligned (4B-aligned) 16-byte global load -> global_load_dwordx4.
__device__ __forceinline__ float4 load_f4u(const float* p) {
    float4 v; __builtin_memcpy(&v, p, 16); return v;
}

__device__ __forceinline__ float fmax4(const float4& v) {
    return fmaxf(fmaxf(v.x, v.y), fmaxf(v.z, v.w));
}
__device__ __forceinline__ float4 fmax44(const float4& a, const float4& b) {
    return make_float4(fmaxf(a.x, b.x), fmaxf(a.y, b.y),
                       fmaxf(a.z, b.z), fmaxf(a.w, b.w));
}

// Focal term, pure registers; row[t] extraction fused as compare-select
// (NO arrays -> NO scratch; dynamic-indexed arrays cost 3x here, R5).
__device__ __forceinline__ float focal_regs(
    int t, const float4& c0, const float4& c1, const float4& c2,
    const float4& c3, const float4& c4, float c20)
{
    float m = fmaxf(fmax4(fmax44(fmax44(c0, c1), fmax44(c2, c3))),
                    fmaxf(fmax4(c4), c20));
    float s = 0.0f, et = 0.0f;
#define FSTEP(val, idx) { float e = __expf((val) - m); s += e; et = (t == (idx)) ? e : et; }
    FSTEP(c0.x, 0)  FSTEP(c0.y, 1)  FSTEP(c0.z, 2)  FSTEP(c0.w, 3)
    FSTEP(c1.x, 4)  FSTEP(c1.y, 5)  FSTEP(c1.z, 6)  FSTEP(c1.w, 7)
    FSTEP(c2.x, 8)  FSTEP(c2.y, 9)  FSTEP(c2.z, 10) FSTEP(c2.w, 11)
    FSTEP(c3.x, 12) FSTEP(c3.y, 13) FSTEP(c3.z, 14) FSTEP(c3.w, 15)
    FSTEP(c4.x, 16) FSTEP(c4.y, 17) FSTEP(c4.z, 18) FSTEP(c4.w, 19)
    FSTEP(c20,  20)
#undef FSTEP
    float pt = et / s;
    pt = fminf(fmaxf(pt, 1e-7f), 1.0f - 1e-7f);
    float om = 1.0f - pt;
    return -__logf(pt) * om * om;
}

__device__ __forceinline__ float smooth_l1(const float4& lp, const float4& lt) {
    float d0 = lp.x - lt.x, d1 = lp.y - lt.y, d2 = lp.z - lt.z, d3 = lp.w - lt.w;
    float a0 = fabsf(d0), a1 = fabsf(d1), a2 = fabsf(d2), a3 = fabsf(d3);
    float s = 0.0f;
    s += (a0 < 1.0f) ? 0.5f * d0 * d0 : a0 - 0.5f;
    s += (a1 < 1.0f) ? 0.5f * d1 * d1 : a1 - 0.5f;
    s += (a2 < 1.0f) ? 0.5f * d2 * d2 : a2 - 0.5f;
    s += (a3 < 1.0f) ? 0.5f * d3 * d3 : a3 - 0.5f;
    return s;
}

// Two-kernel structure: per-block float2 partial + tiny reduce dispatch.
// Single-kernel last-block-done finalize costs +50..+100 us on gfx950
// (same-line agent-scope RMW serialization; measured R5/R8/R9).
__global__ __launch_bounds__(BLK) void focal_main(
    const float* __restrict__ loc_p,
    const float* __restrict__ loc_t,
    const float* __restrict__ cls_p,
    const int*   __restrict__ cls_t,
    float2* __restrict__ partials,
    int n_anchors)
{
    __shared__ float redL[4], redP[4];

    const int tid  = threadIdx.x;
    const int wave = tid >> 6;
    const int lane = tid & 63;
    const long long a0 = (long long)blockIdx.x * SPAN + tid;
    const long long a1 = a0 + BLK;

    float acc = 0.0f, npos = 0.0f;
    const bool v0 = (a0 < n_anchors), v1 = (a1 < n_anchors);

    // ---- all loads in explicit registers, issued before any use ----
    int t0 = -1, t1 = -1;
    float4 lp0, lt0, lp1, lt1;
    float4 c00, c01, c02, c03, c04; float c0_20 = 0.0f;
    float4 c10, c11, c12, c13, c14; float c1_20 = 0.0f;

    if (v0) {
        t0  = cls_t[a0];
        lp0 = ((const float4*)loc_p)[a0];
        lt0 = ((const float4*)loc_t)[a0];
        const float* g = cls_p + a0 * NCLS;
        c00 = load_f4u(g);      c01 = load_f4u(g + 4);  c02 = load_f4u(g + 8);
        c03 = load_f4u(g + 12); c04 = load_f4u(g + 16); c0_20 = g[20];
    }
    if (v1) {
        t1  = cls_t[a1];
        lp1 = ((const float4*)loc_p)[a1];
        lt1 = ((const float4*)loc_t)[a1];
        const float* g = cls_p + a1 * NCLS;
        c10 = load_f4u(g);      c11 = load_f4u(g + 4);  c12 = load_f4u(g + 8);
        c13 = load_f4u(g + 12); c14 = load_f4u(g + 16); c1_20 = g[20];
    }

    // ---- pure-register compute ----
    if (v0) {
        if (t0 > 0)  { acc += smooth_l1(lp0, lt0); npos += 1.0f; }
        if (t0 >= 0) acc += focal_regs(t0, c00, c01, c02, c03, c04, c0_20);
    }
    if (v1) {
        if (t1 > 0)  { acc += smooth_l1(lp1, lt1); npos += 1.0f; }
        if (t1 >= 0) acc += focal_regs(t1, c10, c11, c12, c13, c14, c1_20);
    }

    // ---- wave shuffle -> LDS -> one float2 per block ----
    #pragma unroll
    for (int off = 32; off > 0; off >>= 1) {
        acc  += __shfl_down(acc,  off, 64);
        npos += __shfl_down(npos, off, 64);
    }
    if (lane == 0) { redL[wave] = acc; redP[wave] = npos; }
    __syncthreads();
    if (tid == 0)
        partials[blockIdx.x] = make_float2(redL[0] + redL[1] + redL[2] + redL[3],
                                           redP[0] + redP[1] + redP[2] + redP[3]);
}

#define RBLK 1024
__global__ __launch_bounds__(RBLK) void focal_reduce(
    const float2* __restrict__ partials, float* __restrict__ out, int npart)
{
    __shared__ float red[32];
    float L = 0.0f, P = 0.0f;
    for (int i = threadIdx.x; i < npart; i += RBLK) {
        float2 v = partials[i];
        L += v.x; P += v.y;
    }
    #pragma unroll
    for (int off = 32; off > 0; off >>= 1) {
        L += __shfl_down(L, off, 64);
        P += __shfl_down(P, off, 64);
    }
    const int wave = threadIdx.x >> 6, lane = threadIdx.x & 63;
    if (lane == 0) { red[wave * 2] = L; red[wave * 2 + 1] = P; }
    __syncthreads();
    if (threadIdx.x == 0) {
        float Ls = 0.0f, Ps = 0.0f;
        #pragma unroll
        for (int w = 0; w < RBLK / 64; ++w) { Ls += red[w * 2]; Ps += red[w * 2 + 1]; }
        out[0] = Ls / Ps;
    }
}

extern "C" void kernel_launch(void* const* d_in, const int* in_sizes, int n_in,
                              void* d_out, int out_size, void* d_ws, size_t ws_size,
                              hipStream_t stream)
{
    const float* loc_p = (const float*)d_in[0];
    const float* loc_t = (const float*)d_in[1];
    const float* cls_p = (const float*)d_in[2];
    const int*   cls_t = (const int*)d_in[3];
    // d_in[4] (pos) ignored: pos == (cls_targets > 0) exactly.
    float*  out = (float*)d_out;
    float2* ws  = (float2*)d_ws;

    const int n_anchors = in_sizes[3];                  // B*A = 1,048,576
    const int blocks = (n_anchors + SPAN - 1) / SPAN;   // 2048

    focal_main<<<blocks, BLK, 0, stream>>>(loc_p, loc_t, cls_p, cls_t, ws, n_anchors);
    focal_reduce<<<1, RBLK, 0, stream>>>(ws, out, blocks);
}